// Round 6
// baseline (78.499 us; speedup 1.0000x reference)
//
#include <hip/hip_runtime.h>
#include <hip/hip_bf16.h>
#include <math.h>

#define IN_FEAT 4096
#define OUT_FEAT 4096
#define NCOMP 256
#define BATCH 4096
#define TWO_PI_F 6.28318530717958647692f

typedef __attribute__((ext_vector_type(8))) short short8;
typedef __attribute__((ext_vector_type(8))) __bf16 bf16x8;
typedef __attribute__((ext_vector_type(4))) float f32x4;
typedef __attribute__((ext_vector_type(16))) float f32x16;

// round-to-nearest-even f32 -> bf16
__device__ __forceinline__ ushort f2b(float f) {
  union { float f; unsigned u; } v; v.f = f;
  unsigned r = (v.u + 0x7fffu + ((v.u >> 16) & 1u)) >> 16;
  return (ushort)r;
}

__device__ __forceinline__ float b2f(short s) {
  union { unsigned u; float f; } v; v.u = ((unsigned)(ushort)s) << 16;
  return v.f;
}

__device__ __forceinline__ bf16x8 ld_frag(const void* p) {
  short8 s = *(const short8*)p;
  return __builtin_bit_cast(bf16x8, s);
}

__device__ __forceinline__ bf16x8 cvt8(float4 a, float4 b) {
  short8 h;
  h[0] = (short)f2b(a.x); h[1] = (short)f2b(a.y);
  h[2] = (short)f2b(a.z); h[3] = (short)f2b(a.w);
  h[4] = (short)f2b(b.x); h[5] = (short)f2b(b.y);
  h[6] = (short)f2b(b.z); h[7] = (short)f2b(b.w);
  return __builtin_bit_cast(bf16x8, h);
}

__device__ __forceinline__ void gload_lds16(const ushort* g, ushort* l) {
  __builtin_amdgcn_global_load_lds(
      (const __attribute__((address_space(1))) void*)g,
      (__attribute__((address_space(3))) void*)l, 16, 0, 0);
}

// ---------------------------------------------------------------- prep
__global__ __launch_bounds__(256) void prep_kernel(
    const float* __restrict__ mus, const float* __restrict__ lvs,
    const float* __restrict__ w,
    ushort* __restrict__ Gt, ushort* __restrict__ GoT) {
  int idx = blockIdx.x * 256 + threadIdx.x;
  if (idx < NCOMP * IN_FEAT) {
    int m = idx >> 12, i = idx & (IN_FEAT - 1);
    float v = expf(lvs[2 * m]);
    float d = (float)i * (1.0f / (IN_FEAT - 1)) - mus[2 * m];
    float g = expf(-d * d * (0.5f / v)) * rsqrtf(TWO_PI_F * v) * w[m];
    Gt[idx] = f2b(g);
  } else {
    idx -= NCOMP * IN_FEAT;
    int o = idx >> 8, m = idx & (NCOMP - 1);
    float v = expf(lvs[2 * m + 1]);
    float d = (float)o * (1.0f / (OUT_FEAT - 1)) - mus[2 * m + 1];
    float g = expf(-d * d * (0.5f / v)) * rsqrtf(TWO_PI_F * v);
    GoT[idx] = f2b(g);
  }
}

// ---------------------------------------------------------------- GEMM1
// Cpart[split][4096][256](bf16) = x[64-band, kchunk] @ Gt^T
// 32x32x16 MFMA. BM=64, BN=256; wave w: m[0,64) x n[64w,64w+64) (2x2 frags).
// A: global->reg->cvt, 1-stage prefetch, NEVER waits at barriers (counted
// vmcnt(8) leaves the 8 A-loads in flight). B: gload_lds dbuf, pre-swizzled.
// Raw s_barrier, one per stage.
template<int NS>
__global__ __launch_bounds__(256, 2) void gemm1_kernel(
    const float* __restrict__ x, const ushort* __restrict__ Gt,
    ushort* __restrict__ Cpart) {
  constexpr int KR = IN_FEAT / NS;
  constexpr int NT = KR / 32;  // even for all NS in {1,2,4,8}
  __shared__ __align__(16) ushort Bs[2 * 8192];  // 2 x 16 KB (256n x 32k bf16)
  const int tid = threadIdx.x, wid = tid >> 6, lane = tid & 63;
  const int r32 = lane & 31, h = lane >> 5;
  const int m0 = blockIdx.x * 64;
  const int kb0 = blockIdx.y * KR;

  f32x16 acc[2][2] = {};  // [mi][nj]

  // B staging: 16 chunks of 1 KB (16 n-rows x 64 B); 4/wave; pre-swizzled src
  const int brow = lane >> 2;
  const int bswz = (((lane & 3) ^ ((lane >> 3) & 3)) << 3);  // ushort units
  // fragment-read swizzle (64 B rows)
  const int sw0 = (h << 4) ^ (((r32 >> 1) & 3) << 4);

  // A: lane-private global pointers (row = m0 + r32 / +32, k starts at h*8)
  const float* xlo = &x[(size_t)(m0 + r32) * IN_FEAT + kb0 + h * 8];
  const float* xhi = xlo + (size_t)32 * IN_FEAT;

  #define STAGE_B(buf, kb)                                                   \
    _Pragma("unroll")                                                        \
    for (int q = 0; q < 4; ++q) {                                            \
      int nb = wid * 4 + q;                                                  \
      gload_lds16(&Gt[(size_t)(nb * 16 + brow) * IN_FEAT + (kb) + bswz],     \
                  &Bs[(buf) * 8192 + nb * 512]);                             \
    }

  #define LOAD_A(px, K)                                                      \
    px[0] = *(const float4*)(xlo + (K));                                     \
    px[1] = *(const float4*)(xlo + (K) + 4);                                 \
    px[2] = *(const float4*)(xlo + (K) + 16);                                \
    px[3] = *(const float4*)(xlo + (K) + 20);                                \
    px[4] = *(const float4*)(xhi + (K));                                     \
    px[5] = *(const float4*)(xhi + (K) + 4);                                 \
    px[6] = *(const float4*)(xhi + (K) + 16);                                \
    px[7] = *(const float4*)(xhi + (K) + 20);

  #define COMPUTE(px, buf) {                                                 \
    const char* Bb = (const char*)&Bs[(buf) * 8192];                         \
    bf16x8 al0 = cvt8(px[0], px[1]), al1 = cvt8(px[2], px[3]);               \
    bf16x8 ah0 = cvt8(px[4], px[5]), ah1 = cvt8(px[6], px[7]);               \
    bf16x8 b00 = ld_frag(Bb + (wid * 64 + r32) * 64 + (sw0 ^ 0));            \
    bf16x8 b10 = ld_frag(Bb + (wid * 64 + 32 + r32) * 64 + (sw0 ^ 0));       \
    bf16x8 b01 = ld_frag(Bb + (wid * 64 + r32) * 64 + (sw0 ^ 32));           \
    bf16x8 b11 = ld_frag(Bb + (wid * 64 + 32 + r32) * 64 + (sw0 ^ 32));      \
    acc[0][0] = __builtin_amdgcn_mfma_f32_32x32x16_bf16(al0, b00, acc[0][0], 0, 0, 0); \
    acc[0][1] = __builtin_amdgcn_mfma_f32_32x32x16_bf16(al0, b10, acc[0][1], 0, 0, 0); \
    acc[1][0] = __builtin_amdgcn_mfma_f32_32x32x16_bf16(ah0, b00, acc[1][0], 0, 0, 0); \
    acc[1][1] = __builtin_amdgcn_mfma_f32_32x32x16_bf16(ah0, b10, acc[1][1], 0, 0, 0); \
    acc[0][0] = __builtin_amdgcn_mfma_f32_32x32x16_bf16(al1, b01, acc[0][0], 0, 0, 0); \
    acc[0][1] = __builtin_amdgcn_mfma_f32_32x32x16_bf16(al1, b11, acc[0][1], 0, 0, 0); \
    acc[1][0] = __builtin_amdgcn_mfma_f32_32x32x16_bf16(ah1, b01, acc[1][0], 0, 0, 0); \
    acc[1][1] = __builtin_amdgcn_mfma_f32_32x32x16_bf16(ah1, b11, acc[1][1], 0, 0, 0); }

  #define BAR_V8()                                                           \
    asm volatile("s_waitcnt vmcnt(8)" ::: "memory");                         \
    __builtin_amdgcn_s_barrier();                                            \
    __builtin_amdgcn_sched_barrier(0);

  float4 pe[8], po[8];

  // prologue: B(0) + A(0); vmcnt(8) completes the 4 B-loads, A(0) keeps flying
  STAGE_B(0, kb0)
  LOAD_A(pe, 0)
  BAR_V8()

  int t = 0;
  // steady state: iterations t and t+1, both with full next-stage staging
  for (; t + 1 < NT - 1; t += 2) {
    STAGE_B(1, kb0 + (t + 1) * 32)
    LOAD_A(po, (t + 1) * 32)
    COMPUTE(pe, 0)
    BAR_V8()
    STAGE_B(0, kb0 + (t + 2) * 32)
    LOAD_A(pe, (t + 2) * 32)
    COMPUTE(po, 1)
    BAR_V8()
  }
  // t == NT-2 (NT even): stage last B, then final compute without staging
  STAGE_B(1, kb0 + (t + 1) * 32)
  LOAD_A(po, (t + 1) * 32)
  COMPUTE(pe, 0)
  BAR_V8()
  COMPUTE(po, 1)

  #undef STAGE_B
  #undef LOAD_A
  #undef COMPUTE
  #undef BAR_V8

  ushort* Cp = Cpart + (size_t)blockIdx.y * ((size_t)BATCH * NCOMP);
  #pragma unroll
  for (int mi = 0; mi < 2; ++mi)
    #pragma unroll
    for (int nj = 0; nj < 2; ++nj)
      #pragma unroll
      for (int g = 0; g < 16; ++g) {
        int row = m0 + mi * 32 + (g & 3) + 8 * (g >> 2) + 4 * h;
        int col = wid * 64 + nj * 32 + r32;
        Cp[(size_t)row * NCOMP + col] = f2b(acc[mi][nj][g]);
      }
}

// ---------------------------------------------------------------- reduce
template<int NS>
__global__ __launch_bounds__(256) void reduce_kernel(ushort* __restrict__ Cp) {
  size_t i = ((size_t)blockIdx.x * 256 + threadIdx.x) * 8;
  float s[8] = {};
  #pragma unroll
  for (int p = 0; p < NS; ++p) {
    short8 v = *(const short8*)&Cp[(size_t)p * BATCH * NCOMP + i];
    #pragma unroll
    for (int e = 0; e < 8; ++e) s[e] += b2f(v[e]);
  }
  short8 hh;
  #pragma unroll
  for (int e = 0; e < 8; ++e) hh[e] = (short)f2b(s[e]);
  *(short8*)&Cp[i] = hh;
}

// ---------------------------------------------------------------- GEMM2
// out[4096][4096](f32) = (Cb @ GoT^T) * scale; 32x32x16 MFMA.
// BM=BN=128; wave owns 64x64 (2x2 frags). Stage=32k, dbuf 32 KB.
__global__ __launch_bounds__(256, 4) void gemm2_kernel(
    const ushort* __restrict__ Cb, const ushort* __restrict__ GoT,
    const float* __restrict__ w, float* __restrict__ out) {
  __shared__ __align__(16) ushort lds[2 * 8192];  // per buf: A 8 KB, B 8 KB
  const int tid = threadIdx.x, wid = tid >> 6, lane = tid & 63;
  const int m0 = blockIdx.y * 128, n0 = blockIdx.x * 128;
  const int wr = (wid >> 1) * 64, wc = (wid & 1) * 64;
  const int r32 = lane & 31, h = lane >> 5;

  // fold wsum: per-wave butterfly over the 256 weights
  float4 wv = *(const float4*)&w[lane * 4];
  float s = wv.x + wv.y + wv.z + wv.w;
  #pragma unroll
  for (int off = 32; off > 0; off >>= 1) s += __shfl_xor(s, off);
  const float scale = 1.0f / ((float)IN_FEAT * s);

  const int brow = lane >> 2;
  const int bswz = (((lane & 3) ^ ((lane >> 3) & 3)) << 3);
  const int sw0 = (h << 4) ^ (((r32 >> 1) & 3) << 4);

  f32x16 acc[2][2] = {};

  #define STAGE2(buf, k0)                                                    \
    _Pragma("unroll")                                                        \
    for (int q = 0; q < 2; ++q) {                                            \
      int c = wid * 2 + q;                                                   \
      int row = c * 16 + brow;                                               \
      gload_lds16(&Cb[(size_t)(m0 + row) * NCOMP + (k0) + bswz],             \
                  &lds[(buf) * 8192 + c * 512]);                             \
      gload_lds16(&GoT[(size_t)(n0 + row) * NCOMP + (k0) + bswz],            \
                  &lds[(buf) * 8192 + 4096 + c * 512]);                      \
    }

  STAGE2(0, 0)
  __syncthreads();

  for (int t = 0; t < 8; ++t) {
    if (t < 7) STAGE2((t + 1) & 1, (t + 1) * 32)
    const char* base = (const char*)lds + (t & 1) * 16384;
    const char* Bb = base + 8192;
    #pragma unroll
    for (int s2 = 0; s2 < 2; ++s2) {
      const int off = sw0 ^ (s2 << 5);
      bf16x8 a0 = ld_frag(base + (wr + r32) * 64 + off);
      bf16x8 a1 = ld_frag(base + (wr + 32 + r32) * 64 + off);
      bf16x8 b0 = ld_frag(Bb + (wc + r32) * 64 + off);
      bf16x8 b1 = ld_frag(Bb + (wc + 32 + r32) * 64 + off);
      acc[0][0] = __builtin_amdgcn_mfma_f32_32x32x16_bf16(a0, b0, acc[0][0], 0, 0, 0);
      acc[0][1] = __builtin_amdgcn_mfma_f32_32x32x16_bf16(a0, b1, acc[0][1], 0, 0, 0);
      acc[1][0] = __builtin_amdgcn_mfma_f32_32x32x16_bf16(a1, b0, acc[1][0], 0, 0, 0);
      acc[1][1] = __builtin_amdgcn_mfma_f32_32x32x16_bf16(a1, b1, acc[1][1], 0, 0, 0);
    }
    __syncthreads();
  }
  #undef STAGE2

  #pragma unroll
  for (int mi = 0; mi < 2; ++mi)
    #pragma unroll
    for (int nj = 0; nj < 2; ++nj)
      #pragma unroll
      for (int g = 0; g < 16; ++g) {
        int row = m0 + wr + mi * 32 + (g & 3) + 8 * (g >> 2) + 4 * h;
        int col = n0 + wc + nj * 32 + r32;
        out[(size_t)row * OUT_FEAT + col] = acc[mi][nj][g] * scale;
      }
}

// ---------------------------------------------------------------- launch
extern "C" void kernel_launch(void* const* d_in, const int* in_sizes, int n_in,
                              void* d_out, int out_size, void* d_ws, size_t ws_size,
                              hipStream_t stream) {
  const float* x   = (const float*)d_in[0];
  const float* mus = (const float*)d_in[1];
  const float* lvs = (const float*)d_in[2];
  const float* w   = (const float*)d_in[3];
  float* out = (float*)d_out;

  ushort* Gt  = (ushort*)d_ws;                      // [256][4096] bf16, 2 MiB
  ushort* GoT = Gt  + (size_t)NCOMP * IN_FEAT;      // [4096][256] bf16, 2 MiB
  ushort* Cpart = GoT + (size_t)OUT_FEAT * NCOMP;   // NS x 2 MiB; Cb = Cpart[0]

  const size_t MiB = 1024 * 1024;
  int nsplit = 8;
  while (nsplit > 1 && ws_size < 4 * MiB + (size_t)nsplit * 2 * MiB) nsplit >>= 1;

  prep_kernel<<<(NCOMP * IN_FEAT + OUT_FEAT * NCOMP) / 256, 256, 0, stream>>>(
      mus, lvs, w, Gt, GoT);

  dim3 g1(BATCH / 64, nsplit);
  switch (nsplit) {
    case 8:  gemm1_kernel<8><<<g1, 256, 0, stream>>>(x, Gt, Cpart);
             reduce_kernel<8><<<BATCH * NCOMP / 8 / 256, 256, 0, stream>>>(Cpart);
             break;
    case 4:  gemm1_kernel<4><<<g1, 256, 0, stream>>>(x, Gt, Cpart);
             reduce_kernel<4><<<BATCH * NCOMP / 8 / 256, 256, 0, stream>>>(Cpart);
             break;
    case 2:  gemm1_kernel<2><<<g1, 256, 0, stream>>>(x, Gt, Cpart);
             reduce_kernel<2><<<BATCH * NCOMP / 8 / 256, 256, 0, stream>>>(Cpart);
             break;
    default: gemm1_kernel<1><<<g1, 256, 0, stream>>>(x, Gt, Cpart);
             break;
  }

  gemm2_kernel<<<dim3(OUT_FEAT / 128, BATCH / 128), 256, 0, stream>>>(
      Cpart, GoT, w, out);
}

// Round 7
// 77.728 us; speedup vs baseline: 1.0099x; 1.0099x over previous
//
#include <hip/hip_runtime.h>
#include <hip/hip_bf16.h>
#include <math.h>

#define IN_FEAT 4096
#define OUT_FEAT 4096
#define NCOMP 256
#define BATCH 4096
#define TWO_PI_F 6.28318530717958647692f

typedef __attribute__((ext_vector_type(8))) short short8;
typedef __attribute__((ext_vector_type(8))) __bf16 bf16x8;
typedef __attribute__((ext_vector_type(4))) float f32x4;
typedef __attribute__((ext_vector_type(16))) float f32x16;

// round-to-nearest-even f32 -> bf16 (bit-exact RTNE)
__device__ __forceinline__ ushort f2b(float f) {
  union { float f; unsigned u; } v; v.f = f;
  unsigned r = (v.u + 0x7fffu + ((v.u >> 16) & 1u)) >> 16;
  return (ushort)r;
}

__device__ __forceinline__ float b2f(short s) {
  union { unsigned u; float f; } v; v.u = ((unsigned)(ushort)s) << 16;
  return v.f;
}

__device__ __forceinline__ bf16x8 ld_frag(const void* p) {
  short8 s = *(const short8*)p;
  return __builtin_bit_cast(bf16x8, s);
}

// native casts -> v_cvt_pk_bf16_f32 (RTNE)
__device__ __forceinline__ bf16x8 cvt8f(float4 a, float4 b) {
  bf16x8 r;
  r[0] = (__bf16)a.x; r[1] = (__bf16)a.y; r[2] = (__bf16)a.z; r[3] = (__bf16)a.w;
  r[4] = (__bf16)b.x; r[5] = (__bf16)b.y; r[6] = (__bf16)b.z; r[7] = (__bf16)b.w;
  return r;
}

__device__ __forceinline__ void gload_lds16(const void* g, void* l) {
  __builtin_amdgcn_global_load_lds(
      (const __attribute__((address_space(1))) void*)g,
      (__attribute__((address_space(3))) void*)l, 16, 0, 0);
}

// ---------------------------------------------------------------- prep
__global__ __launch_bounds__(256) void prep_kernel(
    const float* __restrict__ mus, const float* __restrict__ lvs,
    const float* __restrict__ w,
    ushort* __restrict__ Gt, ushort* __restrict__ GoT) {
  int idx = blockIdx.x * 256 + threadIdx.x;
  if (idx < NCOMP * IN_FEAT) {
    int m = idx >> 12, i = idx & (IN_FEAT - 1);
    float v = expf(lvs[2 * m]);
    float d = (float)i * (1.0f / (IN_FEAT - 1)) - mus[2 * m];
    float g = expf(-d * d * (0.5f / v)) * rsqrtf(TWO_PI_F * v) * w[m];
    Gt[idx] = f2b(g);
  } else {
    idx -= NCOMP * IN_FEAT;
    int o = idx >> 8, m = idx & (NCOMP - 1);
    float v = expf(lvs[2 * m + 1]);
    float d = (float)o * (1.0f / (OUT_FEAT - 1)) - mus[2 * m + 1];
    float g = expf(-d * d * (0.5f / v)) * rsqrtf(TWO_PI_F * v);
    GoT[idx] = f2b(g);
  }
}

// ---------------------------------------------------------------- GEMM1
// Cpart[z][4096][256](bf16) = x[64-band, kchunk] @ Gt^T[ n-half, kchunk ]
// BM=64, BN=128, stage=32k. ALL staging via global_load_lds into
// fragment-major LDS (XOR-slot per row -> conflict-free ds_read_b128,
// linear DMA dest, permutation carried by the global source address).
// Depth-2 pipeline, 3 buffers, counted vmcnt(4): each stage's loads get
// ~2 stages to land; never drained to 0 in-loop. 4 gload_lds/wave/stage.
// Per buf 16 KB: A = 64 rows x 128 B f32 (8 KB), B = 128 cols x 64 B bf16.
template<int NS>
__global__ __launch_bounds__(256, 3) void gemm1_kernel(
    const float* __restrict__ x, const ushort* __restrict__ Gt,
    ushort* __restrict__ Cpart) {
  constexpr int KR = IN_FEAT / NS;
  constexpr int NT = KR / 32;  // >= 4 for NS <= 32
  __shared__ __align__(16) ushort lds[3 * 8192];  // 48 KB
  const int tid = threadIdx.x, wid = tid >> 6, lane = tid & 63;
  const int r32 = lane & 31, h = lane >> 5;
  const int m0 = blockIdx.x * 64;
  const int n0 = blockIdx.y * 128;
  const int kb0 = blockIdx.z * KR;
  const int wr = wid >> 1, wc = wid & 1;  // wave = 32m x 64n

  f32x16 acc[2] = {};

  // ---- staging setup: waves 0,1 stage A (x, f32); waves 2,3 stage B (Gt).
  // A chunk c (0..7): rows m0+8c..+8, each row 128 B; lane: row8=l>>3,
  //   slin=(l>>1)&3, q16=l&1; logical slot32 = slin ^ (row8&3);
  //   src float ofs = (slot>>1)*16 + (slot&1)*8 + q16*4.
  // B chunk c (0..7): cols n0+16c..+16, each col 64 B; lane: col16=l>>2,
  //   slin=l&3; logical slot16 = slin ^ (col16&3);
  //   src bf16 ofs = (slot>>1)*16 + (slot&1)*8.
  const char* gp[4];
  int dofs[4];
  int gstride;
  if (wid < 2) {
    gstride = 128;  // 32 floats per stage
    int row8 = lane >> 3, slin = (lane >> 1) & 3, q16 = lane & 1;
    int slot = slin ^ (row8 & 3);
    int kofs = (slot >> 1) * 16 + (slot & 1) * 8 + q16 * 4;
    #pragma unroll
    for (int q = 0; q < 4; ++q) {
      int c = wid * 4 + q;
      gp[q] = (const char*)&x[(size_t)(m0 + c * 8 + row8) * IN_FEAT + kb0 + kofs];
      dofs[q] = c * 1024 + lane * 16;
    }
  } else {
    gstride = 64;  // 32 bf16 per stage
    int col16 = lane >> 2, slin = lane & 3;
    int slot = slin ^ (col16 & 3);
    int kofs = (slot >> 1) * 16 + (slot & 1) * 8;
    #pragma unroll
    for (int q = 0; q < 4; ++q) {
      int c = (wid - 2) * 4 + q;
      gp[q] = (const char*)&Gt[(size_t)(n0 + c * 16 + col16) * IN_FEAT + kb0 + kofs];
      dofs[q] = 8192 + c * 1024 + lane * 16;
    }
  }

  #define STAGE(wb_) {                                                       \
    char* lb = (char*)lds + (wb_) * 16384;                                   \
    _Pragma("unroll")                                                        \
    for (int q = 0; q < 4; ++q) {                                            \
      gload_lds16(gp[q], lb + dofs[q]);                                      \
      gp[q] += gstride;                                                      \
    } }

  // fragment reads: logical (s,h) lives at slot (s*2+h)^(r32&3)
  const int aswz = r32 & 3;
  #define COMPUTE(rb_) {                                                     \
    const char* sb = (const char*)lds + (rb_) * 16384;                       \
    _Pragma("unroll")                                                        \
    for (int s = 0; s < 2; ++s) {                                            \
      const int sa = (s * 2 + h) ^ aswz;                                     \
      const char* ap = sb + (wr * 32 + r32) * 128 + sa * 32;                 \
      float4 f0 = *(const float4*)ap;                                        \
      float4 f1 = *(const float4*)(ap + 16);                                 \
      bf16x8 af = cvt8f(f0, f1);                                             \
      _Pragma("unroll")                                                      \
      for (int nj = 0; nj < 2; ++nj) {                                       \
        const char* bp = sb + 8192 + ((wc * 2 + nj) * 32 + r32) * 64 + sa * 16; \
        bf16x8 bf = ld_frag(bp);                                             \
        acc[nj] = __builtin_amdgcn_mfma_f32_32x32x16_bf16(af, bf, acc[nj], 0, 0, 0); \
      }                                                                      \
    } }

  #define WAITBAR(n)                                                         \
    asm volatile("s_waitcnt vmcnt(" #n ")" ::: "memory");                    \
    __builtin_amdgcn_s_barrier();                                            \
    __builtin_amdgcn_sched_barrier(0);

  // prologue: 2 stages in flight
  STAGE(0)
  STAGE(1)

  int rb = 0, wb = 2;
  for (int t = 0; t < NT - 2; ++t) {
    WAITBAR(4)          // stage t landed; stage t+1 (4 loads/wave) in flight
    STAGE(wb)           // issue stage t+2
    COMPUTE(rb)
    rb = (rb == 2) ? 0 : rb + 1;
    wb = (wb == 2) ? 0 : wb + 1;
  }
  WAITBAR(4)            // stage NT-2 landed, NT-1 in flight
  COMPUTE(rb)
  rb = (rb == 2) ? 0 : rb + 1;
  WAITBAR(0)            // drain final stage
  COMPUTE(rb)

  #undef STAGE
  #undef COMPUTE
  #undef WAITBAR

  ushort* Cp = Cpart + (size_t)blockIdx.z * ((size_t)BATCH * NCOMP);
  #pragma unroll
  for (int nj = 0; nj < 2; ++nj) {
    int col = n0 + wc * 64 + nj * 32 + r32;
    #pragma unroll
    for (int g = 0; g < 16; ++g) {
      int row = m0 + wr * 32 + (g & 3) + 8 * (g >> 2) + 4 * h;
      Cp[(size_t)row * NCOMP + col] = f2b(acc[nj][g]);
    }
  }
}

// ---------------------------------------------------------------- reduce
template<int NS>
__global__ __launch_bounds__(256) void reduce_kernel(ushort* __restrict__ Cp) {
  size_t i = ((size_t)blockIdx.x * 256 + threadIdx.x) * 8;
  float s[8] = {};
  #pragma unroll
  for (int p = 0; p < NS; ++p) {
    short8 v = *(const short8*)&Cp[(size_t)p * BATCH * NCOMP + i];
    #pragma unroll
    for (int e = 0; e < 8; ++e) s[e] += b2f(v[e]);
  }
  short8 hh;
  #pragma unroll
  for (int e = 0; e < 8; ++e) hh[e] = (short)f2b(s[e]);
  *(short8*)&Cp[i] = hh;
}

// ---------------------------------------------------------------- GEMM2
// out[4096][4096](f32) = (Cb @ GoT^T) * scale; 32x32x16 MFMA.
// BM=BN=128; wave owns 64x64 (2x2 frags). Stage=32k, dbuf 32 KB.
__global__ __launch_bounds__(256, 4) void gemm2_kernel(
    const ushort* __restrict__ Cb, const ushort* __restrict__ GoT,
    const float* __restrict__ w, float* __restrict__ out) {
  __shared__ __align__(16) ushort lds[2 * 8192];  // per buf: A 8 KB, B 8 KB
  const int tid = threadIdx.x, wid = tid >> 6, lane = tid & 63;
  const int m0 = blockIdx.y * 128, n0 = blockIdx.x * 128;
  const int wr = (wid >> 1) * 64, wc = (wid & 1) * 64;
  const int r32 = lane & 31, h = lane >> 5;

  // fold wsum: per-wave butterfly over the 256 weights
  float4 wv = *(const float4*)&w[lane * 4];
  float s = wv.x + wv.y + wv.z + wv.w;
  #pragma unroll
  for (int off = 32; off > 0; off >>= 1) s += __shfl_xor(s, off);
  const float scale = 1.0f / ((float)IN_FEAT * s);

  const int brow = lane >> 2;
  const int bswz = (((lane & 3) ^ ((lane >> 3) & 3)) << 3);
  const int sw0 = (h << 4) ^ (((r32 >> 1) & 3) << 4);

  f32x16 acc[2][2] = {};

  #define STAGE2(buf, k0)                                                    \
    _Pragma("unroll")                                                        \
    for (int q = 0; q < 2; ++q) {                                            \
      int c = wid * 2 + q;                                                   \
      int row = c * 16 + brow;                                               \
      gload_lds16(&Cb[(size_t)(m0 + row) * NCOMP + (k0) + bswz],             \
                  &lds[(buf) * 8192 + c * 512]);                             \
      gload_lds16(&GoT[(size_t)(n0 + row) * NCOMP + (k0) + bswz],            \
                  &lds[(buf) * 8192 + 4096 + c * 512]);                      \
    }

  STAGE2(0, 0)
  __syncthreads();

  for (int t = 0; t < 8; ++t) {
    if (t < 7) STAGE2((t + 1) & 1, (t + 1) * 32)
    const char* base = (const char*)lds + (t & 1) * 16384;
    const char* Bb = base + 8192;
    #pragma unroll
    for (int s2 = 0; s2 < 2; ++s2) {
      const int off = sw0 ^ (s2 << 5);
      bf16x8 a0 = ld_frag(base + (wr + r32) * 64 + off);
      bf16x8 a1 = ld_frag(base + (wr + 32 + r32) * 64 + off);
      bf16x8 b0 = ld_frag(Bb + (wc + r32) * 64 + off);
      bf16x8 b1 = ld_frag(Bb + (wc + 32 + r32) * 64 + off);
      acc[0][0] = __builtin_amdgcn_mfma_f32_32x32x16_bf16(a0, b0, acc[0][0], 0, 0, 0);
      acc[0][1] = __builtin_amdgcn_mfma_f32_32x32x16_bf16(a0, b1, acc[0][1], 0, 0, 0);
      acc[1][0] = __builtin_amdgcn_mfma_f32_32x32x16_bf16(a1, b0, acc[1][0], 0, 0, 0);
      acc[1][1] = __builtin_amdgcn_mfma_f32_32x32x16_bf16(a1, b1, acc[1][1], 0, 0, 0);
    }
    __syncthreads();
  }
  #undef STAGE2

  #pragma unroll
  for (int mi = 0; mi < 2; ++mi)
    #pragma unroll
    for (int nj = 0; nj < 2; ++nj)
      #pragma unroll
      for (int g = 0; g < 16; ++g) {
        int row = m0 + wr + mi * 32 + (g & 3) + 8 * (g >> 2) + 4 * h;
        int col = n0 + wc + nj * 32 + r32;
        out[(size_t)row * OUT_FEAT + col] = acc[mi][nj][g] * scale;
      }
}

// ---------------------------------------------------------------- launch
extern "C" void kernel_launch(void* const* d_in, const int* in_sizes, int n_in,
                              void* d_out, int out_size, void* d_ws, size_t ws_size,
                              hipStream_t stream) {
  const float* x   = (const float*)d_in[0];
  const float* mus = (const float*)d_in[1];
  const float* lvs = (const float*)d_in[2];
  const float* w   = (const float*)d_in[3];
  float* out = (float*)d_out;

  ushort* Gt  = (ushort*)d_ws;                      // [256][4096] bf16, 2 MiB
  ushort* GoT = Gt  + (size_t)NCOMP * IN_FEAT;      // [4096][256] bf16, 2 MiB
  ushort* Cpart = GoT + (size_t)OUT_FEAT * NCOMP;   // NS x 2 MiB; Cb = Cpart[0]

  const size_t MiB = 1024 * 1024;
  int nsplit = 8;
  while (nsplit > 1 && ws_size < 4 * MiB + (size_t)nsplit * 2 * MiB) nsplit >>= 1;

  prep_kernel<<<(NCOMP * IN_FEAT + OUT_FEAT * NCOMP) / 256, 256, 0, stream>>>(
      mus, lvs, w, Gt, GoT);

  switch (nsplit) {
    case 8:
      gemm1_kernel<8><<<dim3(BATCH / 64, 2, 8), 256, 0, stream>>>(x, Gt, Cpart);
      reduce_kernel<8><<<BATCH * NCOMP / 8 / 256, 256, 0, stream>>>(Cpart);
      break;
    case 4:
      gemm1_kernel<4><<<dim3(BATCH / 64, 2, 4), 256, 0, stream>>>(x, Gt, Cpart);
      reduce_kernel<4><<<BATCH * NCOMP / 8 / 256, 256, 0, stream>>>(Cpart);
      break;
    case 2:
      gemm1_kernel<2><<<dim3(BATCH / 64, 2, 2), 256, 0, stream>>>(x, Gt, Cpart);
      reduce_kernel<2><<<BATCH * NCOMP / 8 / 256, 256, 0, stream>>>(Cpart);
      break;
    default:
      gemm1_kernel<1><<<dim3(BATCH / 64, 2, 1), 256, 0, stream>>>(x, Gt, Cpart);
      break;
  }

  gemm2_kernel<<<dim3(OUT_FEAT / 128, BATCH / 128), 256, 0, stream>>>(
      Cpart, GoT, w, out);
}

// Round 8
// 75.130 us; speedup vs baseline: 1.0448x; 1.0346x over previous
//
#include <hip/hip_runtime.h>
#include <hip/hip_bf16.h>
#include <math.h>

#define IN_FEAT 4096
#define OUT_FEAT 4096
#define NCOMP 256
#define BATCH 4096
#define TWO_PI_F 6.28318530717958647692f

typedef __attribute__((ext_vector_type(8))) short short8;
typedef __attribute__((ext_vector_type(8))) __bf16 bf16x8;
typedef __attribute__((ext_vector_type(4))) float f32x4;
typedef __attribute__((ext_vector_type(16))) float f32x16;

// round-to-nearest-even f32 -> bf16
__device__ __forceinline__ ushort f2b(float f) {
  union { float f; unsigned u; } v; v.f = f;
  unsigned r = (v.u + 0x7fffu + ((v.u >> 16) & 1u)) >> 16;
  return (ushort)r;
}

__device__ __forceinline__ float b2f(short s) {
  union { unsigned u; float f; } v; v.u = ((unsigned)(ushort)s) << 16;
  return v.f;
}

__device__ __forceinline__ bf16x8 ld_frag(const void* p) {
  short8 s = *(const short8*)p;
  return __builtin_bit_cast(bf16x8, s);
}

// native casts -> v_cvt_pk_bf16_f32 (RTNE)
__device__ __forceinline__ bf16x8 cvt8f(float4 a, float4 b) {
  bf16x8 r;
  r[0] = (__bf16)a.x; r[1] = (__bf16)a.y; r[2] = (__bf16)a.z; r[3] = (__bf16)a.w;
  r[4] = (__bf16)b.x; r[5] = (__bf16)b.y; r[6] = (__bf16)b.z; r[7] = (__bf16)b.w;
  return r;
}

__device__ __forceinline__ void gload_lds16(const void* g, void* l) {
  __builtin_amdgcn_global_load_lds(
      (const __attribute__((address_space(1))) void*)g,
      (__attribute__((address_space(3))) void*)l, 16, 0, 0);
}

// ---------------------------------------------------------------- prep
__global__ __launch_bounds__(256) void prep_kernel(
    const float* __restrict__ mus, const float* __restrict__ lvs,
    const float* __restrict__ w,
    ushort* __restrict__ Gt, ushort* __restrict__ GoT) {
  int idx = blockIdx.x * 256 + threadIdx.x;
  if (idx < NCOMP * IN_FEAT) {
    int m = idx >> 12, i = idx & (IN_FEAT - 1);
    float v = expf(lvs[2 * m]);
    float d = (float)i * (1.0f / (IN_FEAT - 1)) - mus[2 * m];
    float g = expf(-d * d * (0.5f / v)) * rsqrtf(TWO_PI_F * v) * w[m];
    Gt[idx] = f2b(g);
  } else {
    idx -= NCOMP * IN_FEAT;
    int o = idx >> 8, m = idx & (NCOMP - 1);
    float v = expf(lvs[2 * m + 1]);
    float d = (float)o * (1.0f / (OUT_FEAT - 1)) - mus[2 * m + 1];
    float g = expf(-d * d * (0.5f / v)) * rsqrtf(TWO_PI_F * v);
    GoT[idx] = f2b(g);
  }
}

// ---------------------------------------------------------------- GEMM1
// Cpart[z][4096][256](bf16) = x[64-band, kchunk] @ Gt^T[n-slice, kchunk]
// BM=64, BN=128, BK=32. Grid (64,2,NS): NS=8 -> 1024 blocks = 4/CU fully
// resident (the real latency-hiding lever: 16 waves/CU TLP).
// B: gload_lds, 3 buffers, depth-2 counted vmcnt(6) (loads get ~2 stages to
// land; never drained in-loop). R2's zero-conflict swizzle. A: global->reg
// (pe/po double-buffer), cvt in-reg. 4 waves = 2m x 2n, wave = 32m x 64n,
// 16x16x32 MFMA, 8/stage.
template<int NS>
__global__ __launch_bounds__(256, 4) void gemm1_kernel(
    const float* __restrict__ x, const ushort* __restrict__ Gt,
    ushort* __restrict__ Cpart) {
  constexpr int KR = IN_FEAT / NS;
  constexpr int NT = KR / 32;  // >= 16, even
  __shared__ __align__(16) ushort Bs[3 * 4096];  // 3 x 8 KB ([128 n][32 k])
  const int tid = threadIdx.x, wid = tid >> 6, lane = tid & 63;
  const int m0 = blockIdx.x * 64;
  const int n0 = blockIdx.y * 128;
  const int kb0 = blockIdx.z * KR;
  const int wr = wid >> 1, wc = wid & 1;
  const int l15 = lane & 15;

  f32x4 acc[2][4] = {};  // [mi][nj] 16x16 frags

  // B staging: 8 chunks of 1 KB (16 n-rows x 64 B), 2/wave; pre-swizzled src
  const int brow = lane >> 2;
  const int bswz = (((lane & 3) ^ ((lane >> 3) & 3)) << 3);  // ushort units
  const ushort* gb[2];
  #pragma unroll
  for (int q = 0; q < 2; ++q) {
    int c = wid * 2 + q;
    gb[q] = &Gt[(size_t)(n0 + c * 16 + brow) * IN_FEAT + kb0 + bswz];
  }
  // fragment-read swizzle (64 B rows, 4 x 16 B slots)
  const int fswz = ((lane >> 4) << 4) ^ (((l15 >> 1) & 3) << 4);

  // A: lane-private rows m0 + wr*32 + l15 (+16), k = kb0 + (lane>>4)*8
  const float* xp0 = &x[(size_t)(m0 + wr * 32 + l15) * IN_FEAT + kb0 + ((lane >> 4) << 3)];
  const float* xp1 = xp0 + (size_t)16 * IN_FEAT;

  #define STAGE_B(buf, krel)                                                 \
    _Pragma("unroll")                                                        \
    for (int q = 0; q < 2; ++q)                                              \
      gload_lds16(gb[q] + (krel), &Bs[(buf) * 4096 + (wid * 2 + q) * 512]);

  #define LOAD_A(P, krel)                                                    \
    P[0] = *(const float4*)(xp0 + (krel));                                   \
    P[1] = *(const float4*)(xp0 + (krel) + 4);                               \
    P[2] = *(const float4*)(xp1 + (krel));                                   \
    P[3] = *(const float4*)(xp1 + (krel) + 4);

  #define COMPUTE(P, rb_) {                                                  \
    const char* Bb = (const char*)Bs + (rb_) * 8192;                         \
    bf16x8 a0 = cvt8f(P[0], P[1]);                                           \
    bf16x8 a1 = cvt8f(P[2], P[3]);                                           \
    _Pragma("unroll")                                                        \
    for (int nj = 0; nj < 4; ++nj) {                                         \
      bf16x8 bf = ld_frag(Bb + (wc * 64 + nj * 16 + l15) * 64 + fswz);       \
      acc[0][nj] = __builtin_amdgcn_mfma_f32_16x16x32_bf16(a0, bf, acc[0][nj], 0, 0, 0); \
      acc[1][nj] = __builtin_amdgcn_mfma_f32_16x16x32_bf16(a1, bf, acc[1][nj], 0, 0, 0); \
    } }

  #define WAITBAR(n)                                                         \
    asm volatile("s_waitcnt vmcnt(" #n ")" ::: "memory");                    \
    __builtin_amdgcn_s_barrier();                                            \
    __builtin_amdgcn_sched_barrier(0);

  float4 pe[4], po[4];

  // prologue: 2 B-stages + A(0) in flight
  STAGE_B(0, 0)
  STAGE_B(1, 32)
  LOAD_A(pe, 0)

  int rb = 0, wb = 2;
  for (int t = 0; t < NT - 2; t += 2) {
    WAITBAR(6)                       // B(t) landed; B(t+1)+A(t) may fly
    STAGE_B(wb, (t + 2) * 32)
    LOAD_A(po, (t + 1) * 32)
    COMPUTE(pe, rb)
    rb = (rb == 2) ? 0 : rb + 1; wb = (wb == 2) ? 0 : wb + 1;
    WAITBAR(6)
    STAGE_B(wb, (t + 3) * 32)
    LOAD_A(pe, (t + 2) * 32)
    COMPUTE(po, rb)
    rb = (rb == 2) ? 0 : rb + 1; wb = (wb == 2) ? 0 : wb + 1;
  }
  // stage NT-2: nothing left to stage; B(NT-2) is older than the 6 in flight
  WAITBAR(6)
  LOAD_A(po, (NT - 1) * 32)
  COMPUTE(pe, rb)
  rb = (rb == 2) ? 0 : rb + 1;
  // stage NT-1: clear B(NT-1) (the 4 newest are A(NT-1))
  WAITBAR(4)
  COMPUTE(po, rb)

  #undef STAGE_B
  #undef LOAD_A
  #undef COMPUTE
  #undef WAITBAR

  ushort* Cp = Cpart + (size_t)blockIdx.z * ((size_t)BATCH * NCOMP);
  #pragma unroll
  for (int mi = 0; mi < 2; ++mi)
    #pragma unroll
    for (int nj = 0; nj < 4; ++nj)
      #pragma unroll
      for (int r = 0; r < 4; ++r) {
        int row = m0 + wr * 32 + mi * 16 + (lane >> 4) * 4 + r;
        int col = n0 + wc * 64 + nj * 16 + l15;
        Cp[(size_t)row * NCOMP + col] = f2b(acc[mi][nj][r]);
      }
}

// ---------------------------------------------------------------- reduce
template<int NS>
__global__ __launch_bounds__(256) void reduce_kernel(ushort* __restrict__ Cp) {
  size_t i = ((size_t)blockIdx.x * 256 + threadIdx.x) * 8;
  float s[8] = {};
  #pragma unroll
  for (int p = 0; p < NS; ++p) {
    short8 v = *(const short8*)&Cp[(size_t)p * BATCH * NCOMP + i];
    #pragma unroll
    for (int e = 0; e < 8; ++e) s[e] += b2f(v[e]);
  }
  short8 hh;
  #pragma unroll
  for (int e = 0; e < 8; ++e) hh[e] = (short)f2b(s[e]);
  *(short8*)&Cp[i] = hh;
}

// ---------------------------------------------------------------- GEMM2
// out[4096][4096](f32) = (Cb @ GoT^T) * scale; 32x32x16 MFMA.
// BM=BN=128; wave owns 64x64 (2x2 frags). Stage=32k, dbuf 32 KB.
__global__ __launch_bounds__(256, 4) void gemm2_kernel(
    const ushort* __restrict__ Cb, const ushort* __restrict__ GoT,
    const float* __restrict__ w, float* __restrict__ out) {
  __shared__ __align__(16) ushort lds[2 * 8192];  // per buf: A 8 KB, B 8 KB
  const int tid = threadIdx.x, wid = tid >> 6, lane = tid & 63;
  const int m0 = blockIdx.y * 128, n0 = blockIdx.x * 128;
  const int wr = (wid >> 1) * 64, wc = (wid & 1) * 64;
  const int r32 = lane & 31, h = lane >> 5;

  float4 wv = *(const float4*)&w[lane * 4];
  float s = wv.x + wv.y + wv.z + wv.w;
  #pragma unroll
  for (int off = 32; off > 0; off >>= 1) s += __shfl_xor(s, off);
  const float scale = 1.0f / ((float)IN_FEAT * s);

  const int brow = lane >> 2;
  const int bswz = (((lane & 3) ^ ((lane >> 3) & 3)) << 3);
  const int sw0 = ((lane >> 5) << 4) ^ (((r32 >> 1) & 3) << 4);

  f32x16 acc[2][2] = {};

  #define STAGE2(buf, k0)                                                    \
    _Pragma("unroll")                                                        \
    for (int q = 0; q < 2; ++q) {                                            \
      int c = wid * 2 + q;                                                   \
      int row = c * 16 + brow;                                               \
      gload_lds16(&Cb[(size_t)(m0 + row) * NCOMP + (k0) + bswz],             \
                  &lds[(buf) * 8192 + c * 512]);                             \
      gload_lds16(&GoT[(size_t)(n0 + row) * NCOMP + (k0) + bswz],            \
                  &lds[(buf) * 8192 + 4096 + c * 512]);                      \
    }

  STAGE2(0, 0)
  __syncthreads();

  for (int t = 0; t < 8; ++t) {
    if (t < 7) STAGE2((t + 1) & 1, (t + 1) * 32)
    const char* base = (const char*)lds + (t & 1) * 16384;
    const char* Bb = base + 8192;
    #pragma unroll
    for (int s2 = 0; s2 < 2; ++s2) {
      const int off = sw0 ^ (s2 << 5);
      bf16x8 a0 = ld_frag(base + (wr + r32) * 64 + off);
      bf16x8 a1 = ld_frag(base + (wr + 32 + r32) * 64 + off);
      bf16x8 b0 = ld_frag(Bb + (wc + r32) * 64 + off);
      bf16x8 b1 = ld_frag(Bb + (wc + 32 + r32) * 64 + off);
      acc[0][0] = __builtin_amdgcn_mfma_f32_32x32x16_bf16(a0, b0, acc[0][0], 0, 0, 0);
      acc[0][1] = __builtin_amdgcn_mfma_f32_32x32x16_bf16(a0, b1, acc[0][1], 0, 0, 0);
      acc[1][0] = __builtin_amdgcn_mfma_f32_32x32x16_bf16(a1, b0, acc[1][0], 0, 0, 0);
      acc[1][1] = __builtin_amdgcn_mfma_f32_32x32x16_bf16(a1, b1, acc[1][1], 0, 0, 0);
    }
    __syncthreads();
  }
  #undef STAGE2

  #pragma unroll
  for (int mi = 0; mi < 2; ++mi)
    #pragma unroll
    for (int nj = 0; nj < 2; ++nj)
      #pragma unroll
      for (int g = 0; g < 16; ++g) {
        int row = m0 + wr + mi * 32 + (g & 3) + 8 * (g >> 2) + 4 * h;
        int col = n0 + wc + nj * 32 + r32;
        out[(size_t)row * OUT_FEAT + col] = acc[mi][nj][g] * scale;
      }
}

// ---------------------------------------------------------------- launch
extern "C" void kernel_launch(void* const* d_in, const int* in_sizes, int n_in,
                              void* d_out, int out_size, void* d_ws, size_t ws_size,
                              hipStream_t stream) {
  const float* x   = (const float*)d_in[0];
  const float* mus = (const float*)d_in[1];
  const float* lvs = (const float*)d_in[2];
  const float* w   = (const float*)d_in[3];
  float* out = (float*)d_out;

  ushort* Gt  = (ushort*)d_ws;                      // [256][4096] bf16, 2 MiB
  ushort* GoT = Gt  + (size_t)NCOMP * IN_FEAT;      // [4096][256] bf16, 2 MiB
  ushort* Cpart = GoT + (size_t)OUT_FEAT * NCOMP;   // NS x 2 MiB; Cb = Cpart[0]

  const size_t MiB = 1024 * 1024;
  int nsplit = 8;
  while (nsplit > 1 && ws_size < 4 * MiB + (size_t)nsplit * 2 * MiB) nsplit >>= 1;

  prep_kernel<<<(NCOMP * IN_FEAT + OUT_FEAT * NCOMP) / 256, 256, 0, stream>>>(
      mus, lvs, w, Gt, GoT);

  switch (nsplit) {
    case 8:
      gemm1_kernel<8><<<dim3(BATCH / 64, 2, 8), 256, 0, stream>>>(x, Gt, Cpart);
      reduce_kernel<8><<<BATCH * NCOMP / 8 / 256, 256, 0, stream>>>(Cpart);
      break;
    case 4:
      gemm1_kernel<4><<<dim3(BATCH / 64, 2, 4), 256, 0, stream>>>(x, Gt, Cpart);
      reduce_kernel<4><<<BATCH * NCOMP / 8 / 256, 256, 0, stream>>>(Cpart);
      break;
    case 2:
      gemm1_kernel<2><<<dim3(BATCH / 64, 2, 2), 256, 0, stream>>>(x, Gt, Cpart);
      reduce_kernel<2><<<BATCH * NCOMP / 8 / 256, 256, 0, stream>>>(Cpart);
      break;
    default:
      gemm1_kernel<1><<<dim3(BATCH / 64, 2, 1), 256, 0, stream>>>(x, Gt, Cpart);
      break;
  }

  gemm2_kernel<<<dim3(OUT_FEAT / 128, BATCH / 128), 256, 0, stream>>>(
      Cpart, GoT, w, out);
}

// Round 9
// 58.061 us; speedup vs baseline: 1.3520x; 1.2940x over previous
//
#include <hip/hip_runtime.h>
#include <hip/hip_bf16.h>
#include <math.h>

#define IN_FEAT 4096
#define OUT_FEAT 4096
#define NCOMP 256
#define BATCH 4096
#define TWO_PI_F 6.28318530717958647692f

typedef __attribute__((ext_vector_type(8))) short short8;
typedef __attribute__((ext_vector_type(8))) __bf16 bf16x8;
typedef __attribute__((ext_vector_type(4))) float f32x4;
typedef __attribute__((ext_vector_type(16))) float f32x16;

// round-to-nearest-even f32 -> bf16
__device__ __forceinline__ ushort f2b(float f) {
  union { float f; unsigned u; } v; v.f = f;
  unsigned r = (v.u + 0x7fffu + ((v.u >> 16) & 1u)) >> 16;
  return (ushort)r;
}

__device__ __forceinline__ float b2f(short s) {
  union { unsigned u; float f; } v; v.u = ((unsigned)(ushort)s) << 16;
  return v.f;
}

__device__ __forceinline__ bf16x8 ld_frag(const void* p) {
  short8 s = *(const short8*)p;
  return __builtin_bit_cast(bf16x8, s);
}

// native casts -> v_cvt_pk_bf16_f32 (RTNE)
__device__ __forceinline__ bf16x8 cvt8f(float4 a, float4 b) {
  bf16x8 r;
  r[0] = (__bf16)a.x; r[1] = (__bf16)a.y; r[2] = (__bf16)a.z; r[3] = (__bf16)a.w;
  r[4] = (__bf16)b.x; r[5] = (__bf16)b.y; r[6] = (__bf16)b.z; r[7] = (__bf16)b.w;
  return r;
}

__device__ __forceinline__ void gload_lds16(const void* g, void* l) {
  __builtin_amdgcn_global_load_lds(
      (const __attribute__((address_space(1))) void*)g,
      (__attribute__((address_space(3))) void*)l, 16, 0, 0);
}

// ---------------------------------------------------------------- prep
__global__ __launch_bounds__(256) void prep_kernel(
    const float* __restrict__ mus, const float* __restrict__ lvs,
    const float* __restrict__ w,
    ushort* __restrict__ Gt, ushort* __restrict__ GoT) {
  int idx = blockIdx.x * 256 + threadIdx.x;
  if (idx < NCOMP * IN_FEAT) {
    int m = idx >> 12, i = idx & (IN_FEAT - 1);
    float v = expf(lvs[2 * m]);
    float d = (float)i * (1.0f / (IN_FEAT - 1)) - mus[2 * m];
    float g = expf(-d * d * (0.5f / v)) * rsqrtf(TWO_PI_F * v) * w[m];
    Gt[idx] = f2b(g);
  } else {
    idx -= NCOMP * IN_FEAT;
    int o = idx >> 8, m = idx & (NCOMP - 1);
    float v = expf(lvs[2 * m + 1]);
    float d = (float)o * (1.0f / (OUT_FEAT - 1)) - mus[2 * m + 1];
    float g = expf(-d * d * (0.5f / v)) * rsqrtf(TWO_PI_F * v);
    GoT[idx] = f2b(g);
  }
}

// ---------------------------------------------------------------- GEMM1
// Cpart[z][4096][256](bf16) = x[128-band, kchunk] @ Gt^T[128 n, kchunk]
// BM=128, BN=128, BK=32. ALL staging via global_load_lds (A incl.: chunk =
// 8 rows x 128 B is lane-linear; source pre-swizzled slot^=row&7, rule 21).
// 3 buffers (24 KB each: A 16 KB f32 + B 8 KB bf16), depth-2, constant
// vmcnt(6): S(t+1) never drained in-loop. Wave = 64m x 64n, 16 MFMA/stage.
// Grid (32, 2, NS): NS=8 -> 512 blocks = 2/CU resident (72 KB LDS).
template<int NS>
__global__ __launch_bounds__(256, 2) void gemm1_kernel(
    const float* __restrict__ x, const ushort* __restrict__ Gt,
    ushort* __restrict__ Cpart) {
  constexpr int KR = IN_FEAT / NS;
  constexpr int NT = KR / 32;  // 16 at NS=8
  __shared__ __align__(16) char lds[3 * 24576];  // 72 KB
  const int tid = threadIdx.x, wid = tid >> 6, lane = tid & 63;
  const int m0 = blockIdx.x * 128;
  const int n0 = blockIdx.y * 128;
  const int kb0 = blockIdx.z * KR;
  const int l15 = lane & 15, q = lane >> 4;
  const int wr = (wid >> 1) * 64, wc = (wid & 1) * 64;

  f32x4 acc[4][4] = {};  // [mi][nj] 16x16 frags

  // A staging: 16 chunks (8 rows x 128 B f32), 4/wave; src slot ^= row&7
  const int ar = lane >> 3;                  // row in chunk (0..7)
  const int aslot = (lane & 7) ^ ar;         // source logical 16B slot
  const float* gpa[4];
  #pragma unroll
  for (int i = 0; i < 4; ++i) {
    int c = wid * 4 + i;
    gpa[i] = &x[(size_t)(m0 + c * 8 + ar) * IN_FEAT + kb0 + aslot * 4];
  }
  // B staging: 8 chunks (16 rows x 64 B bf16), 2/wave; R2 zero-conflict swz
  const int br = lane >> 2;
  const int bsw = (((lane & 3) ^ ((lane >> 3) & 3)) << 3);  // ushort units
  const ushort* gpb[2];
  #pragma unroll
  for (int i = 0; i < 2; ++i) {
    int c = wid * 2 + i;
    gpb[i] = &Gt[(size_t)(n0 + c * 16 + br) * IN_FEAT + kb0 + bsw];
  }
  // B fragment-read swizzle (64 B rows, 4 x 16 B slots)
  const int fswz = (q << 4) ^ (((l15 >> 1) & 3) << 4);
  // A fragment-read slot keys
  const int akey = l15 & 7;

  #define STAGE(wb_, krel) {                                                 \
    char* Ld = lds + (wb_) * 24576;                                          \
    _Pragma("unroll")                                                        \
    for (int i = 0; i < 4; ++i)                                              \
      gload_lds16(gpa[i] + (krel), Ld + (wid * 4 + i) * 1024 + lane * 16);   \
    _Pragma("unroll")                                                        \
    for (int i = 0; i < 2; ++i)                                              \
      gload_lds16(gpb[i] + (krel),                                           \
                  Ld + 16384 + (wid * 2 + i) * 1024 + lane * 16);            \
  }

  #define COMPUTE(rb_) {                                                     \
    const char* Ab = lds + (rb_) * 24576;                                    \
    const char* Bb = Ab + 16384;                                             \
    bf16x8 bfr[4];                                                           \
    _Pragma("unroll")                                                        \
    for (int nj = 0; nj < 4; ++nj)                                           \
      bfr[nj] = ld_frag(Bb + (wc + nj * 16 + l15) * 64 + fswz);              \
    _Pragma("unroll")                                                        \
    for (int mi = 0; mi < 4; ++mi) {                                         \
      int mr = wr + mi * 16 + l15;                                           \
      float4 f0 = *(const float4*)(Ab + mr * 128 + (((2 * q + 0) ^ akey) << 4)); \
      float4 f1 = *(const float4*)(Ab + mr * 128 + (((2 * q + 1) ^ akey) << 4)); \
      bf16x8 af = cvt8f(f0, f1);                                             \
      _Pragma("unroll")                                                      \
      for (int nj = 0; nj < 4; ++nj)                                         \
        acc[mi][nj] = __builtin_amdgcn_mfma_f32_16x16x32_bf16(af, bfr[nj],   \
                                                   acc[mi][nj], 0, 0, 0);    \
    } }

  #define WAITBAR(n)                                                         \
    asm volatile("s_waitcnt vmcnt(" #n ")" ::: "memory");                    \
    __builtin_amdgcn_s_barrier();                                            \
    __builtin_amdgcn_sched_barrier(0);

  // prologue: 2 stages in flight
  STAGE(0, 0)
  STAGE(1, 32)

  int rb = 0, wb = 2;
  for (int t = 0; t < NT - 2; ++t) {
    WAITBAR(6)                 // S(t) landed; S(t+1) stays in flight
    STAGE(wb, (t + 2) * 32)    // issue S(t+2)
    COMPUTE(rb)
    rb = (rb == 2) ? 0 : rb + 1;
    wb = (wb == 2) ? 0 : wb + 1;
  }
  WAITBAR(6)                   // S(NT-2) landed, S(NT-1) in flight
  COMPUTE(rb)
  rb = (rb == 2) ? 0 : rb + 1;
  WAITBAR(0)                   // drain final stage
  COMPUTE(rb)

  #undef STAGE
  #undef COMPUTE
  #undef WAITBAR

  ushort* Cp = Cpart + (size_t)blockIdx.z * ((size_t)BATCH * NCOMP);
  #pragma unroll
  for (int mi = 0; mi < 4; ++mi)
    #pragma unroll
    for (int nj = 0; nj < 4; ++nj)
      #pragma unroll
      for (int r = 0; r < 4; ++r) {
        int row = m0 + wr + mi * 16 + q * 4 + r;
        int col = n0 + wc + nj * 16 + l15;
        Cp[(size_t)row * NCOMP + col] = f2b(acc[mi][nj][r]);
      }
}

// ---------------------------------------------------------------- reduce
template<int NS>
__global__ __launch_bounds__(256) void reduce_kernel(ushort* __restrict__ Cp) {
  size_t i = ((size_t)blockIdx.x * 256 + threadIdx.x) * 8;
  float s[8] = {};
  #pragma unroll
  for (int p = 0; p < NS; ++p) {
    short8 v = *(const short8*)&Cp[(size_t)p * BATCH * NCOMP + i];
    #pragma unroll
    for (int e = 0; e < 8; ++e) s[e] += b2f(v[e]);
  }
  short8 hh;
  #pragma unroll
  for (int e = 0; e < 8; ++e) hh[e] = (short)f2b(s[e]);
  *(short8*)&Cp[i] = hh;
}

// ---------------------------------------------------------------- GEMM2
// out[4096][4096](f32) = (Cb @ GoT^T) * scale; 32x32x16 MFMA.
// BM=BN=128; wave owns 64x64 (2x2 frags). Stage=32k, dbuf 32 KB.
__global__ __launch_bounds__(256, 4) void gemm2_kernel(
    const ushort* __restrict__ Cb, const ushort* __restrict__ GoT,
    const float* __restrict__ w, float* __restrict__ out) {
  __shared__ __align__(16) ushort lds[2 * 8192];  // per buf: A 8 KB, B 8 KB
  const int tid = threadIdx.x, wid = tid >> 6, lane = tid & 63;
  const int m0 = blockIdx.y * 128, n0 = blockIdx.x * 128;
  const int wr = (wid >> 1) * 64, wc = (wid & 1) * 64;
  const int r32 = lane & 31, h = lane >> 5;

  float4 wv = *(const float4*)&w[lane * 4];
  float s = wv.x + wv.y + wv.z + wv.w;
  #pragma unroll
  for (int off = 32; off > 0; off >>= 1) s += __shfl_xor(s, off);
  const float scale = 1.0f / ((float)IN_FEAT * s);

  const int brow = lane >> 2;
  const int bswz = (((lane & 3) ^ ((lane >> 3) & 3)) << 3);
  const int sw0 = (h << 4) ^ (((r32 >> 1) & 3) << 4);

  f32x16 acc[2][2] = {};

  #define STAGE2(buf, k0)                                                    \
    _Pragma("unroll")                                                        \
    for (int q2 = 0; q2 < 2; ++q2) {                                         \
      int c = wid * 2 + q2;                                                  \
      int row = c * 16 + brow;                                               \
      gload_lds16(&Cb[(size_t)(m0 + row) * NCOMP + (k0) + bswz],             \
                  &lds[(buf) * 8192 + c * 512]);                             \
      gload_lds16(&GoT[(size_t)(n0 + row) * NCOMP + (k0) + bswz],            \
                  &lds[(buf) * 8192 + 4096 + c * 512]);                      \
    }

  STAGE2(0, 0)
  __syncthreads();

  for (int t = 0; t < 8; ++t) {
    if (t < 7) STAGE2((t + 1) & 1, (t + 1) * 32)
    const char* base = (const char*)lds + (t & 1) * 16384;
    const char* Bb = base + 8192;
    #pragma unroll
    for (int s2 = 0; s2 < 2; ++s2) {
      const int off = sw0 ^ (s2 << 5);
      bf16x8 a0 = ld_frag(base + (wr + r32) * 64 + off);
      bf16x8 a1 = ld_frag(base + (wr + 32 + r32) * 64 + off);
      bf16x8 b0 = ld_frag(Bb + (wc + r32) * 64 + off);
      bf16x8 b1 = ld_frag(Bb + (wc + 32 + r32) * 64 + off);
      acc[0][0] = __builtin_amdgcn_mfma_f32_32x32x16_bf16(a0, b0, acc[0][0], 0, 0, 0);
      acc[0][1] = __builtin_amdgcn_mfma_f32_32x32x16_bf16(a0, b1, acc[0][1], 0, 0, 0);
      acc[1][0] = __builtin_amdgcn_mfma_f32_32x32x16_bf16(a1, b0, acc[1][0], 0, 0, 0);
      acc[1][1] = __builtin_amdgcn_mfma_f32_32x32x16_bf16(a1, b1, acc[1][1], 0, 0, 0);
    }
    __syncthreads();
  }
  #undef STAGE2

  #pragma unroll
  for (int mi = 0; mi < 2; ++mi)
    #pragma unroll
    for (int nj = 0; nj < 2; ++nj)
      #pragma unroll
      for (int g = 0; g < 16; ++g) {
        int row = m0 + wr + mi * 32 + (g & 3) + 8 * (g >> 2) + 4 * h;
        int col = n0 + wc + nj * 32 + r32;
        out[(size_t)row * OUT_FEAT + col] = acc[mi][nj][g] * scale;
      }
}

// ---------------------------------------------------------------- launch
extern "C" void kernel_launch(void* const* d_in, const int* in_sizes, int n_in,
                              void* d_out, int out_size, void* d_ws, size_t ws_size,
                              hipStream_t stream) {
  const float* x   = (const float*)d_in[0];
  const float* mus = (const float*)d_in[1];
  const float* lvs = (const float*)d_in[2];
  const float* w   = (const float*)d_in[3];
  float* out = (float*)d_out;

  ushort* Gt  = (ushort*)d_ws;                      // [256][4096] bf16, 2 MiB
  ushort* GoT = Gt  + (size_t)NCOMP * IN_FEAT;      // [4096][256] bf16, 2 MiB
  ushort* Cpart = GoT + (size_t)OUT_FEAT * NCOMP;   // NS x 2 MiB; Cb = Cpart[0]

  const size_t MiB = 1024 * 1024;
  int nsplit = 8;
  while (nsplit > 1 && ws_size < 4 * MiB + (size_t)nsplit * 2 * MiB) nsplit >>= 1;

  prep_kernel<<<(NCOMP * IN_FEAT + OUT_FEAT * NCOMP) / 256, 256, 0, stream>>>(
      mus, lvs, w, Gt, GoT);

  switch (nsplit) {
    case 8:
      gemm1_kernel<8><<<dim3(BATCH / 128, 2, 8), 256, 0, stream>>>(x, Gt, Cpart);
      reduce_kernel<8><<<BATCH * NCOMP / 8 / 256, 256, 0, stream>>>(Cpart);
      break;
    case 4:
      gemm1_kernel<4><<<dim3(BATCH / 128, 2, 4), 256, 0, stream>>>(x, Gt, Cpart);
      reduce_kernel<4><<<BATCH * NCOMP / 8 / 256, 256, 0, stream>>>(Cpart);
      break;
    case 2:
      gemm1_kernel<2><<<dim3(BATCH / 128, 2, 2), 256, 0, stream>>>(x, Gt, Cpart);
      reduce_kernel<2><<<BATCH * NCOMP / 8 / 256, 256, 0, stream>>>(Cpart);
      break;
    default:
      gemm1_kernel<1><<<dim3(BATCH / 128, 2, 1), 256, 0, stream>>>(x, Gt, Cpart);
      break;
  }

  gemm2_kernel<<<dim3(OUT_FEAT / 128, BATCH / 128), 256, 0, stream>>>(
      Cpart, GoT, w, out);
}